// Round 5
// baseline (245.895 us; speedup 1.0000x reference)
//
#include <hip/hip_runtime.h>
#include <math.h>

// GaussianAdjacencyMatrix: out[b,i,j] = m*exp(-||x_i-x_j||^2/sigma^2) / (row_sum + 1e-8)
// B=8, N=2048, D=3.
// Block = 256 threads, 8 rows. Two-phase, ONE barrier per block:
//  phase 1: all 8 rows' masked-exp partial sums (16 float4 loads in flight,
//           nothing stored per-element -> no spill, no per-row vmcnt(0) drain)
//  phase 2: re-read masks (L2/L3 hit), recompute exp, scale, nt-store.
// Exp recompute trades idle VALU (15% busy) for the removal of 8 per-row
// barrier drains that were capping memory-level parallelism.

#define NN 2048
#define THREADS 256
#define RPB 8
#define EPS 1e-8f

typedef float nfloat4 __attribute__((ext_vector_type(4)));  // native vec for nt-store

__global__ __launch_bounds__(THREADS) void gauss_adj_kernel(
    const float* __restrict__ coords,   // [B, N, 3]
    const float* __restrict__ masks,    // [B, N, N]
    const float* __restrict__ sigma,    // [1]
    float* __restrict__ out)            // [B, N, N]
{
    const int rows_base = blockIdx.x * RPB;
    const int b   = rows_base >> 11;           // / 2048
    const int ib  = rows_base & (NN - 1);      // first row index within batch
    const int tid = threadIdx.x;
    const int wave = tid >> 6;
    const int lane = tid & 63;

    __shared__ float srow[RPB * 3];   // this block's 8 row-centers (x,y,z)
    __shared__ float red[4][RPB];     // per-wave partial sums, [wave][row]

    const float* cb = coords + (size_t)b * NN * 3;
    if (tid < RPB * 3) srow[tid] = cb[ib * 3 + tid];

    // This thread's 8 columns: chunks j4 = c*256+tid (c=0,1), cols 4*j4..4*j4+3.
    const float4* cb4 = (const float4*)cb;
    float xs[2][4], ys[2][4], zs[2][4];
    #pragma unroll
    for (int c = 0; c < 2; ++c) {
        const int j4 = c * THREADS + tid;
        const float4 f0 = cb4[3 * j4 + 0];
        const float4 f1 = cb4[3 * j4 + 1];
        const float4 f2 = cb4[3 * j4 + 2];
        xs[c][0] = f0.x; ys[c][0] = f0.y; zs[c][0] = f0.z;
        xs[c][1] = f0.w; ys[c][1] = f1.x; zs[c][1] = f1.y;
        xs[c][2] = f1.z; ys[c][2] = f1.w; zs[c][2] = f2.x;
        xs[c][3] = f2.y; ys[c][3] = f2.z; zs[c][3] = f2.w;
    }

    const float s = sigma[0];
    const float inv_s2 = 1.0f / (s * s);

    __syncthreads();   // srow ready

    const float4* mbase = (const float4*)(masks + (size_t)rows_base * NN);

    // ---------------- phase 1: row sums, no per-element state ----------------
    float lsum[RPB];
    #pragma unroll
    for (int r = 0; r < RPB; ++r) lsum[r] = 0.0f;

    #pragma unroll
    for (int r = 0; r < RPB; ++r) {
        const float xi = srow[r * 3 + 0];
        const float yi = srow[r * 3 + 1];
        const float zi = srow[r * 3 + 2];
        #pragma unroll
        for (int c = 0; c < 2; ++c) {
            const float4 m = mbase[r * (NN / 4) + c * THREADS + tid];
            const float mm[4] = {m.x, m.y, m.z, m.w};
            #pragma unroll
            for (int q = 0; q < 4; ++q) {
                const float dx = xi - xs[c][q];
                const float dy = yi - ys[c][q];
                const float dz = zi - zs[c][q];
                lsum[r] += __expf(-(dx * dx + dy * dy + dz * dz) * inv_s2) * mm[q];
            }
        }
    }

    // butterfly each of the 8 sums across the wave, then ONE barrier
    #pragma unroll
    for (int r = 0; r < RPB; ++r) {
        #pragma unroll
        for (int off = 1; off < 64; off <<= 1)
            lsum[r] += __shfl_xor(lsum[r], off, 64);
    }
    if (lane == 0) {
        #pragma unroll
        for (int r = 0; r < RPB; ++r) red[wave][r] = lsum[r];
    }
    __syncthreads();

    float invv[RPB];
    #pragma unroll
    for (int r = 0; r < RPB; ++r)
        invv[r] = 1.0f / (red[0][r] + red[1][r] + red[2][r] + red[3][r] + EPS);

    // ---------------- phase 2: recompute, scale, nt-store; no barriers ------
    #pragma unroll
    for (int r = 0; r < RPB; ++r) {
        const float xi = srow[r * 3 + 0];
        const float yi = srow[r * 3 + 1];
        const float zi = srow[r * 3 + 2];
        const float inv = invv[r];
        nfloat4* orow = (nfloat4*)(out + (size_t)(rows_base + r) * NN);
        #pragma unroll
        for (int c = 0; c < 2; ++c) {
            const float4 m = mbase[r * (NN / 4) + c * THREADS + tid];
            const float mm[4] = {m.x, m.y, m.z, m.w};
            nfloat4 o;
            float ov[4];
            #pragma unroll
            for (int q = 0; q < 4; ++q) {
                const float dx = xi - xs[c][q];
                const float dy = yi - ys[c][q];
                const float dz = zi - zs[c][q];
                ov[q] = __expf(-(dx * dx + dy * dy + dz * dz) * inv_s2) * mm[q] * inv;
            }
            o.x = ov[0]; o.y = ov[1]; o.z = ov[2]; o.w = ov[3];
            __builtin_nontemporal_store(o, &orow[c * THREADS + tid]);
        }
    }
}

extern "C" void kernel_launch(void* const* d_in, const int* in_sizes, int n_in,
                              void* d_out, int out_size, void* d_ws, size_t ws_size,
                              hipStream_t stream) {
    const float* coords = (const float*)d_in[0];   // [B,N,3]
    const float* masks  = (const float*)d_in[1];   // [B,N,N]
    const float* sigma  = (const float*)d_in[2];   // [1]
    float* out = (float*)d_out;

    const int B = in_sizes[0] / (NN * 3);
    const int rows = B * NN;
    gauss_adj_kernel<<<rows / RPB, THREADS, 0, stream>>>(coords, masks, sigma, out);
}